// Round 1
// baseline (291.894 us; speedup 1.0000x reference)
//
#include <hip/hip_runtime.h>
#include <hip/hip_bf16.h>
#include <hip/hip_fp16.h>

#define IN_FT  128
#define OUT_FT 32
#define APITCH 136   // f16 pitch for A tile: 272B rows, benign b128 bank pattern

typedef _Float16 f16x8 __attribute__((ext_vector_type(8)));
typedef __attribute__((ext_vector_type(4))) float f32x4;

union H2 { unsigned u; _Float16 h[2]; };

// ---- one-shot: build swizzled f16 weight fragment table (8 KB, L2-hot) ----
// wtab[tile][kt][lane][j] = w[kt*32 + (lane>>4)*8 + j][(lane&15) + tile*16]
__global__ __launch_bounds__(256) void gcn_swz(const float* __restrict__ w,
                                               _Float16* __restrict__ wtab) {
    int t = threadIdx.x;
    for (int i = t; i < 2 * 4 * 64 * 8; i += 256) {
        int j    = i & 7;
        int lane = (i >> 3) & 63;
        int kt   = (i >> 9) & 3;
        int tile = i >> 11;
        int k    = kt * 32 + (lane >> 4) * 8 + j;
        int c    = (lane & 15) + tile * 16;
        wtab[i] = (_Float16)w[k * OUT_FT + c];
    }
}

// ---- sup(f16) = seq @ w via MFMA with LDS-staged coalesced A ----
__global__ __launch_bounds__(256) void gcn_gemm_mfma(const float* __restrict__ seq,
                                                     const _Float16* __restrict__ wtab,
                                                     unsigned short* __restrict__ sup,
                                                     int n) {
    __shared__ __align__(16) _Float16 at[64 * APITCH];   // 17 KB
    const int t    = threadIdx.x;
    const int base = blockIdx.x * 64;

    // stage A tile: 64 rows x 128 f32 -> f16, coalesced global reads.
    for (int it = 0; it < 4; ++it) {
        int i     = it * 256 + t;
        int row_l = i >> 4;
        int c     = i & 15;
        int row   = base + row_l;
        f16x8 v = (f16x8)0;
        if (row < n) {
            const float4* p = (const float4*)(seq + (size_t)row * IN_FT + c * 8);
            float4 lo = p[0], hi = p[1];
            v[0] = (_Float16)lo.x; v[1] = (_Float16)lo.y;
            v[2] = (_Float16)lo.z; v[3] = (_Float16)lo.w;
            v[4] = (_Float16)hi.x; v[5] = (_Float16)hi.y;
            v[6] = (_Float16)hi.z; v[7] = (_Float16)hi.w;
        }
        *(f16x8*)&at[row_l * APITCH + c * 8] = v;
    }
    __syncthreads();

    const int wave = t >> 6;
    const int lane = t & 63;
    const int m    = lane & 15;
    const int quad = lane >> 4;

    const f16x8* wt = (const f16x8*)wtab;
    const int arow_l = wave * 16 + m;

    f32x4 acc0 = {0.f, 0.f, 0.f, 0.f};
    f32x4 acc1 = {0.f, 0.f, 0.f, 0.f};

    for (int kt = 0; kt < 4; ++kt) {
        f16x8 a  = *(const f16x8*)&at[arow_l * APITCH + kt * 32 + quad * 8];
        f16x8 b0 = wt[(0 * 4 + kt) * 64 + lane];
        f16x8 b1 = wt[(1 * 4 + kt) * 64 + lane];
        acc0 = __builtin_amdgcn_mfma_f32_16x16x32_f16(a, b0, acc0, 0, 0, 0);
        acc1 = __builtin_amdgcn_mfma_f32_16x16x32_f16(a, b1, acc1, 0, 0, 0);
    }

    // C/D layout: col = lane&15, row = quad*4 + reg
    for (int i = 0; i < 4; ++i) {
        int ro = base + wave * 16 + quad * 4 + i;
        if (ro < n) {
            _Float16 h0 = (_Float16)acc0[i];
            _Float16 h1 = (_Float16)acc1[i];
            sup[(size_t)ro * OUT_FT + m]      = *(unsigned short*)&h0;
            sup[(size_t)ro * OUT_FT + 16 + m] = *(unsigned short*)&h1;
        }
    }
}

// ---- CSR build phase 1: degree histogram into rs[] (pre-zeroed) ----
__global__ __launch_bounds__(256) void gcn_hist(const int* __restrict__ erow,
                                                int* __restrict__ rs, int nE) {
    int i = blockIdx.x * 256 + threadIdx.x;
    if (i < nE) atomicAdd(&rs[erow[i]], 1);
}

// ---- phase 2a: per-1024-chunk exclusive scan of rs in place; chunk totals -> csum ----
__global__ __launch_bounds__(256) void gcn_scanA(int* __restrict__ rs,
                                                 int* __restrict__ csum, int n) {
    __shared__ int lds[256];
    const int t    = threadIdx.x;
    const int base = blockIdx.x * 1024 + t * 4;   // n % 4 == 0
    int v0 = 0, v1 = 0, v2 = 0, v3 = 0;
    if (base < n) {
        int4 vv = *(const int4*)&rs[base];
        v0 = vv.x; v1 = vv.y; v2 = vv.z; v3 = vv.w;
    }
    int s = v0 + v1 + v2 + v3;
    lds[t] = s;
    __syncthreads();
    for (int o = 1; o < 256; o <<= 1) {
        int x = (t >= o) ? lds[t - o] : 0;
        __syncthreads();
        lds[t] += x;
        __syncthreads();
    }
    int excl = lds[t] - s;
    if (base < n) {
        int4 w;
        w.x = excl;
        w.y = excl + v0;
        w.z = excl + v0 + v1;
        w.w = excl + v0 + v1 + v2;
        *(int4*)&rs[base] = w;
    }
    if (t == 255) csum[blockIdx.x] = lds[255];
}

// ---- phase 2b: exclusive scan of chunk totals (nc <= 256) ----
__global__ __launch_bounds__(256) void gcn_scanB(int* __restrict__ csum, int nc) {
    __shared__ int lds[256];
    int t = threadIdx.x;
    int v = (t < nc) ? csum[t] : 0;
    lds[t] = v;
    __syncthreads();
    for (int o = 1; o < 256; o <<= 1) {
        int x = (t >= o) ? lds[t - o] : 0;
        __syncthreads();
        lds[t] += x;
        __syncthreads();
    }
    if (t < nc) csum[t] = lds[t] - v;
}

// ---- phase 2c: add chunk offsets -> rs[i] = global exclusive start of node i ----
__global__ __launch_bounds__(256) void gcn_scanC(int* __restrict__ rs,
                                                 const int* __restrict__ csum, int n) {
    int base = blockIdx.x * 1024 + threadIdx.x * 4;
    if (base < n) {
        int add = csum[blockIdx.x];
        int4 v = *(const int4*)&rs[base];
        v.x += add; v.y += add; v.z += add; v.w += add;
        *(int4*)&rs[base] = v;
    }
}

// ---- phase 3: scatter edges into CSR slots; rs[r] is consumed start->end ----
// csr entry: col (17 bits, n<2^17) << 15 | val quantized to 15-bit fixed point
__global__ __launch_bounds__(256) void gcn_reorder(const int* __restrict__ erow,
                                                   const int* __restrict__ ecol,
                                                   const float* __restrict__ eval,
                                                   int* __restrict__ rs,
                                                   unsigned* __restrict__ csr, int nE) {
    int i = blockIdx.x * 256 + threadIdx.x;
    if (i >= nE) return;
    int      r = erow[i];
    unsigned c = (unsigned)ecol[i];
    unsigned q = (unsigned)(eval[i] * 32767.f + 0.5f);
    int      p = atomicAdd(&rs[r], 1);
    csr[p] = (c << 15) | q;
}

// ---- phase 4: gather + f32 accumulate + fused relu. 16 lanes per node, ----
// lane j owns output cols {2j, 2j+1}. After reorder, rs[i] = end of segment i,
// so start_i = rs[i-1] (or 0).
__global__ __launch_bounds__(256) void gcn_gather(const int* __restrict__ rs,
                                                  const unsigned* __restrict__ csr,
                                                  const unsigned* __restrict__ sup32,
                                                  float2* __restrict__ out, int n) {
    int g    = blockIdx.x * 256 + threadIdx.x;
    int node = g >> 4;
    if (node >= n) return;
    int j     = g & 15;
    int start = node ? rs[node - 1] : 0;
    int end   = rs[node];

    float a0 = 0.f, a1 = 0.f;
    int e = start;
    for (; e + 2 <= end; e += 2) {          // 2-edge unroll for load ILP
        unsigned p0 = csr[e], p1 = csr[e + 1];
        H2 s0; s0.u = sup32[(p0 >> 15) * 16 + j];
        H2 s1; s1.u = sup32[(p1 >> 15) * 16 + j];
        float v0 = (float)(p0 & 0x7fffu) * (1.f / 32767.f);
        float v1 = (float)(p1 & 0x7fffu) * (1.f / 32767.f);
        a0 += v0 * (float)s0.h[0] + v1 * (float)s1.h[0];
        a1 += v0 * (float)s0.h[1] + v1 * (float)s1.h[1];
    }
    if (e < end) {
        unsigned p0 = csr[e];
        H2 s0; s0.u = sup32[(p0 >> 15) * 16 + j];
        float v0 = (float)(p0 & 0x7fffu) * (1.f / 32767.f);
        a0 += v0 * (float)s0.h[0];
        a1 += v0 * (float)s0.h[1];
    }
    float2 o;
    o.x = fmaxf(a0, 0.f);
    o.y = fmaxf(a1, 0.f);
    out[(size_t)node * 16 + j] = o;
}

extern "C" void kernel_launch(void* const* d_in, const int* in_sizes, int n_in,
                              void* d_out, int out_size, void* d_ws, size_t ws_size,
                              hipStream_t stream) {
    const float* seq  = (const float*)d_in[0];
    const float* w    = (const float*)d_in[1];
    const int*   erow = (const int*)d_in[2];
    const int*   ecol = (const int*)d_in[3];
    const float* eval = (const float*)d_in[4];
    float* out = (float*)d_out;

    const int n_nodes = in_sizes[0] / IN_FT;
    const int n_edges = in_sizes[2];

    // workspace: sup f16 (6.4 MB) | csr u32 (6.4 MB) | rs (0.4 MB) | csum | wtab
    unsigned short* sup  = (unsigned short*)d_ws;
    unsigned*       csr  = (unsigned*)(sup + (size_t)n_nodes * OUT_FT);
    int*            rs   = (int*)(csr + n_edges);
    int*            csum = rs + n_nodes;
    _Float16*       wtab = (_Float16*)(csum + 512);

    // 1) swizzled weight table + dense projection sup = seq @ w (f16)
    gcn_swz<<<1, 256, 0, stream>>>(w, wtab);
    gcn_gemm_mfma<<<(n_nodes + 63) / 64, 256, 0, stream>>>(seq, wtab, sup, n_nodes);

    // 2) CSR build: zero degrees -> histogram -> 3-pass scan -> reorder
    hipMemsetAsync(rs, 0, (size_t)n_nodes * sizeof(int), stream);
    gcn_hist<<<(n_edges + 255) / 256, 256, 0, stream>>>(erow, rs, n_edges);
    int nc = (n_nodes + 1023) / 1024;      // 98 for N=100000 (<=256 required)
    gcn_scanA<<<nc, 256, 0, stream>>>(rs, csum, n_nodes);
    gcn_scanB<<<1, 256, 0, stream>>>(csum, nc);
    gcn_scanC<<<nc, 256, 0, stream>>>(rs, csum, n_nodes);
    gcn_reorder<<<(n_edges + 255) / 256, 256, 0, stream>>>(erow, ecol, eval, rs, csr,
                                                           n_edges);

    // 3) gather + fused relu (atomic-free, f32 accumulation)
    long long gw = (long long)n_nodes * 16;
    gcn_gather<<<(int)((gw + 255) / 256), 256, 0, stream>>>(rs, csr,
                                                            (const unsigned*)sup,
                                                            (float2*)out, n_nodes);
}

// Round 2
// 204.893 us; speedup vs baseline: 1.4246x; 1.4246x over previous
//
#include <hip/hip_runtime.h>
#include <hip/hip_bf16.h>
#include <hip/hip_fp16.h>

#define IN_FT  128
#define OUT_FT 32
#define APITCH 136   // f16 pitch for A tile: 272B rows, benign b128 bank pattern

#define RPB        256          // rows per sort bucket (bucket = row >> 8)
#define HIST_BLKS  256          // extra blocks fused into gemm dispatch for histogram
#define PA_EPT     16           // passA edges per thread
#define PA_EPB     (PA_EPT * 256)

typedef _Float16 f16x8 __attribute__((ext_vector_type(8)));
typedef __attribute__((ext_vector_type(4))) float f32x4;

union H2 { unsigned u; _Float16 h[2]; };

// ---- K1: build swizzled f16 weight table (8 KB) + zero bucket counters ----
// wtab[tile][kt][lane][j] = w[kt*32 + (lane>>4)*8 + j][(lane&15) + tile*16]
__global__ __launch_bounds__(256) void gcn_swz(const float* __restrict__ w,
                                               _Float16* __restrict__ wtab,
                                               int* __restrict__ bb) {
    int t = threadIdx.x;
    bb[t] = 0;
    bb[t + 256] = 0;
    for (int i = t; i < 2 * 4 * 64 * 8; i += 256) {
        int j    = i & 7;
        int lane = (i >> 3) & 63;
        int kt   = (i >> 9) & 3;
        int tile = i >> 11;
        int k    = kt * 32 + (lane >> 4) * 8 + j;
        int c    = (lane & 15) + tile * 16;
        wtab[i] = (_Float16)w[k * OUT_FT + c];
    }
}

// ---- K2: fused  [blocks 0..gb)   : sup(f16) = seq @ w via MFMA
//                 [blocks gb..gb+HIST_BLKS) : bucket histogram of erow ----
__global__ __launch_bounds__(256) void gcn_gemm_hist(const float* __restrict__ seq,
                                                     const _Float16* __restrict__ wtab,
                                                     unsigned short* __restrict__ sup,
                                                     const int* __restrict__ erow,
                                                     int* __restrict__ bb,
                                                     int n, int nE, int gb, int nB) {
    __shared__ __align__(16) _Float16 at[64 * APITCH];   // 17 KB (aliased by hist)
    const int t = threadIdx.x;

    if ((int)blockIdx.x >= gb) {
        // ---------- histogram branch ----------
        int* cnt = (int*)at;
        cnt[t] = 0;
        cnt[t + 256] = 0;
        __syncthreads();
        int hb    = blockIdx.x - gb;
        int chunk = (nE + HIST_BLKS - 1) / HIST_BLKS;
        int cb    = hb * chunk;
        int ce    = min(cb + chunk, nE);
        for (int i = cb + t; i < ce; i += 256)
            atomicAdd(&cnt[erow[i] >> 8], 1);
        __syncthreads();
        for (int b = t; b < nB; b += 256)
            if (cnt[b]) atomicAdd(&bb[b], cnt[b]);
        return;
    }

    // ---------- gemm branch ----------
    const int base = blockIdx.x * 64;

    for (int it = 0; it < 4; ++it) {
        int i     = it * 256 + t;
        int row_l = i >> 4;
        int c     = i & 15;
        int row   = base + row_l;
        f16x8 v = (f16x8)0;
        if (row < n) {
            const float4* p = (const float4*)(seq + (size_t)row * IN_FT + c * 8);
            float4 lo = p[0], hi = p[1];
            v[0] = (_Float16)lo.x; v[1] = (_Float16)lo.y;
            v[2] = (_Float16)lo.z; v[3] = (_Float16)lo.w;
            v[4] = (_Float16)hi.x; v[5] = (_Float16)hi.y;
            v[6] = (_Float16)hi.z; v[7] = (_Float16)hi.w;
        }
        *(f16x8*)&at[row_l * APITCH + c * 8] = v;
    }
    __syncthreads();

    const int wave = t >> 6;
    const int lane = t & 63;
    const int m    = lane & 15;
    const int quad = lane >> 4;

    const f16x8* wt = (const f16x8*)wtab;
    const int arow_l = wave * 16 + m;

    f32x4 acc0 = {0.f, 0.f, 0.f, 0.f};
    f32x4 acc1 = {0.f, 0.f, 0.f, 0.f};

    for (int kt = 0; kt < 4; ++kt) {
        f16x8 a  = *(const f16x8*)&at[arow_l * APITCH + kt * 32 + quad * 8];
        f16x8 b0 = wt[(0 * 4 + kt) * 64 + lane];
        f16x8 b1 = wt[(1 * 4 + kt) * 64 + lane];
        acc0 = __builtin_amdgcn_mfma_f32_16x16x32_f16(a, b0, acc0, 0, 0, 0);
        acc1 = __builtin_amdgcn_mfma_f32_16x16x32_f16(a, b1, acc1, 0, 0, 0);
    }

    // C/D layout: col = lane&15, row = quad*4 + reg
    for (int i = 0; i < 4; ++i) {
        int ro = base + wave * 16 + quad * 4 + i;
        if (ro < n) {
            _Float16 h0 = (_Float16)acc0[i];
            _Float16 h1 = (_Float16)acc1[i];
            sup[(size_t)ro * OUT_FT + m]      = *(unsigned short*)&h0;
            sup[(size_t)ro * OUT_FT + 16 + m] = *(unsigned short*)&h1;
        }
    }
}

// ---- K3: exclusive scan of nB bucket counts (nB <= 512), single block ----
// outputs: bbase[0..nB] (exclusive, sentinel = nE), bptr copy, rs[n] = nE
__global__ __launch_bounds__(512) void gcn_scan(const int* __restrict__ bb,
                                                int* __restrict__ bbase,
                                                int* __restrict__ bptr,
                                                int* __restrict__ rs,
                                                int nB, int n, int nE) {
    __shared__ int lds[512];
    int t = threadIdx.x;
    int v = (t < nB) ? bb[t] : 0;
    lds[t] = v;
    __syncthreads();
    for (int o = 1; o < 512; o <<= 1) {
        int x = (t >= o) ? lds[t - o] : 0;
        __syncthreads();
        lds[t] += x;
        __syncthreads();
    }
    int excl = lds[t] - v;
    if (t < nB) {
        bbase[t] = excl;
        bptr[t]  = excl;
        if (t == nB - 1) bbase[nB] = excl + v;   // == nE
    }
    if (t == 0) rs[n] = nE;
}

// ---- K4: pass A — bin edges into bucket-grouped ebin with block-run writes --
// ebin[i] = { .x = (col<<15)|val15, .y = row }
__global__ __launch_bounds__(256) void gcn_binA(const int* __restrict__ erow,
                                                const int* __restrict__ ecol,
                                                const float* __restrict__ eval,
                                                int* __restrict__ bptr,
                                                uint2* __restrict__ ebin,
                                                int nE, int nB) {
    __shared__ int cnt[512];
    __shared__ int cur[512];
    const int t  = threadIdx.x;
    const int cb = blockIdx.x * PA_EPB;

    cnt[t] = 0;
    cnt[t + 256] = 0;
    __syncthreads();

    // phase 1: local histogram
    for (int k = 0; k < PA_EPT; ++k) {
        int i = cb + k * 256 + t;
        if (i < nE) atomicAdd(&cnt[erow[i] >> 8], 1);
    }
    __syncthreads();

    // phase 2: reserve one contiguous run per non-empty bucket
    for (int b = t; b < nB; b += 256)
        cur[b] = cnt[b] ? atomicAdd(&bptr[b], cnt[b]) : 0;
    __syncthreads();

    // phase 3: place edges (runs land contiguously; same-XCD L2 merges lines)
    for (int k = 0; k < PA_EPT; ++k) {
        int i = cb + k * 256 + t;
        if (i < nE) {
            int      r = erow[i];
            unsigned c = (unsigned)ecol[i];
            unsigned q = (unsigned)(eval[i] * 32767.f + 0.5f);
            int      p = atomicAdd(&cur[r >> 8], 1);
            uint2 e;
            e.x = (c << 15) | q;
            e.y = (unsigned)r;
            ebin[p] = e;
        }
    }
}

// ---- K5: pass B — one block per bucket: row-sort into csr + write rs starts --
__global__ __launch_bounds__(256) void gcn_binB(const int* __restrict__ bbase,
                                                const uint2* __restrict__ ebin,
                                                unsigned* __restrict__ csr,
                                                int* __restrict__ rs, int n) {
    __shared__ int hist[256];
    __shared__ int scanb[256];
    __shared__ int cursor[256];
    const int t     = threadIdx.x;
    const int b     = blockIdx.x;
    const int start = bbase[b];
    const int end   = bbase[b + 1];

    hist[t] = 0;
    __syncthreads();

    // local row histogram (rows b*256 .. b*256+255)
    for (int i = start + t; i < end; i += 256)
        atomicAdd(&hist[ebin[i].y & 255], 1);
    __syncthreads();

    // exclusive scan of 256 counts
    int v = hist[t];
    scanb[t] = v;
    __syncthreads();
    for (int o = 1; o < 256; o <<= 1) {
        int x = (t >= o) ? scanb[t - o] : 0;
        __syncthreads();
        scanb[t] += x;
        __syncthreads();
    }
    int excl = scanb[t] - v;
    cursor[t] = excl;

    // rs starts (coalesced)
    int r0 = b * 256 + t;
    if (r0 < n) rs[r0] = start + excl;
    __syncthreads();

    // placement — scattered 4B writes confined to this block's 16 KB csr slice
    for (int i = start + t; i < end; i += 256) {
        uint2 e = ebin[i];
        int   p = atomicAdd(&cursor[e.y & 255], 1);
        csr[start + p] = e.x;
    }
}

// ---- K6: gather + f32 accumulate + fused relu; 16 lanes per node ----
__global__ __launch_bounds__(256) void gcn_gather(const int* __restrict__ rs,
                                                  const unsigned* __restrict__ csr,
                                                  const unsigned* __restrict__ sup32,
                                                  float2* __restrict__ out, int n) {
    int g    = blockIdx.x * 256 + threadIdx.x;
    int node = g >> 4;
    if (node >= n) return;
    int j     = g & 15;
    int start = rs[node];
    int end   = rs[node + 1];

    float a0 = 0.f, a1 = 0.f;
    int e = start;
    for (; e + 2 <= end; e += 2) {          // 2-edge unroll for load ILP
        unsigned p0 = csr[e], p1 = csr[e + 1];
        H2 s0; s0.u = sup32[(p0 >> 15) * 16 + j];
        H2 s1; s1.u = sup32[(p1 >> 15) * 16 + j];
        float v0 = (float)(p0 & 0x7fffu) * (1.f / 32767.f);
        float v1 = (float)(p1 & 0x7fffu) * (1.f / 32767.f);
        a0 += v0 * (float)s0.h[0] + v1 * (float)s1.h[0];
        a1 += v0 * (float)s0.h[1] + v1 * (float)s1.h[1];
    }
    if (e < end) {
        unsigned p0 = csr[e];
        H2 s0; s0.u = sup32[(p0 >> 15) * 16 + j];
        float v0 = (float)(p0 & 0x7fffu) * (1.f / 32767.f);
        a0 += v0 * (float)s0.h[0];
        a1 += v0 * (float)s0.h[1];
    }
    float2 o;
    o.x = fmaxf(a0, 0.f);
    o.y = fmaxf(a1, 0.f);
    out[(size_t)node * 16 + j] = o;
}

extern "C" void kernel_launch(void* const* d_in, const int* in_sizes, int n_in,
                              void* d_out, int out_size, void* d_ws, size_t ws_size,
                              hipStream_t stream) {
    const float* seq  = (const float*)d_in[0];
    const float* w    = (const float*)d_in[1];
    const int*   erow = (const int*)d_in[2];
    const int*   ecol = (const int*)d_in[3];
    const float* eval = (const float*)d_in[4];
    float* out = (float*)d_out;

    const int n_nodes = in_sizes[0] / IN_FT;
    const int n_edges = in_sizes[2];
    const int nB      = (n_nodes + RPB - 1) / RPB;    // 391 for N=100000 (<=512)

    // workspace layout (all 8B-aligned):
    //   sup   : n*32 u16      (6.4 MB)
    //   csr   : E u32         (6.4 MB)
    //   ebin  : E uint2       (12.8 MB)
    //   rs    : (n+1) int
    //   bbase : (nB+1) int | bptr : nB int | bb : 512 int
    //   wtab  : 4096 f16      (8 KB)
    unsigned short* sup   = (unsigned short*)d_ws;
    unsigned*       csr   = (unsigned*)(sup + (size_t)n_nodes * OUT_FT);
    uint2*          ebin  = (uint2*)(csr + n_edges);
    int*            rs    = (int*)(ebin + n_edges);
    int*            bbase = rs + (n_nodes + 1);
    int*            bptr  = bbase + (nB + 1);
    int*            bb    = bptr + nB;
    _Float16*       wtab  = (_Float16*)(bb + 512);

    // K1: weight table + zero bucket counters
    gcn_swz<<<1, 256, 0, stream>>>(w, wtab, bb);

    // K2: gemm (gb blocks) fused with bucket histogram (HIST_BLKS blocks)
    int gb = (n_nodes + 63) / 64;
    gcn_gemm_hist<<<gb + HIST_BLKS, 256, 0, stream>>>(seq, wtab, sup, erow, bb,
                                                      n_nodes, n_edges, gb, nB);

    // K3: scan bucket counts -> bbase/bptr, rs sentinel
    gcn_scan<<<1, 512, 0, stream>>>(bb, bbase, bptr, rs, nB, n_nodes, n_edges);

    // K4: pass A — bucket-grouped binning (coalesced run writes)
    gcn_binA<<<(n_edges + PA_EPB - 1) / PA_EPB, 256, 0, stream>>>(erow, ecol, eval,
                                                                  bptr, ebin,
                                                                  n_edges, nB);

    // K5: pass B — per-bucket row sort into csr + rs starts
    gcn_binB<<<nB, 256, 0, stream>>>(bbase, ebin, csr, rs, n_nodes);

    // K6: gather + fused relu (atomic-free, f32 accumulation)
    long long gw = (long long)n_nodes * 16;
    gcn_gather<<<(int)((gw + 255) / 256), 256, 0, stream>>>(rs, csr,
                                                            (const unsigned*)sup,
                                                            (float2*)out, n_nodes);
}